// Round 7
// baseline (48.780 us; speedup 1.0000x reference)
//
#include <hip/hip_runtime.h>
#include <math.h>

#define BB 4
#define CC 19
#define NPIX (512 * 1024)       // 524288 per image
#define NB 80                   // histogram bins over max_prob in [0,1]
#define CONF_BIN 72             // 0.9 * 80 exactly -> bin>=72 <=> p>=0.9
#define FRACTION_F 0.66f
#define ROW (CC * NB)           // 1520
#define NROW (BB * CC)          // 76

#define NBLK1 256               // one block per CU
#define BPI (NBLK1 / BB)        // 64 blocks per image
#define SEG (NPIX / BPI)        // 8192 px per block
#define CHUNK 512               // px per staged chunk (== T1, 1 px/thread)
#define NCHUNK (SEG / CHUNK)    // 16
#define T1 512
#define BUFELE (CHUNK * CC)     // 9728 floats = 38912 B per buffer
#define NBUF 3                  // triple buffer, issue 2 chunks ahead

// ws layout:
//   int   cntPart[NBLK1][ROW]   (1.56 MB)
//   float snlPart[NBLK1][ROW]   (1.56 MB)

__device__ __forceinline__ void gload16(const float* g, float* l) {
    // async global->LDS, 16 B/lane; LDS dest = wave-uniform base + lane*16
    __builtin_amdgcn_global_load_lds(
        (const __attribute__((address_space(1))) unsigned int*)g,
        (__attribute__((address_space(3))) unsigned int*)l, 16, 0, 0);
}

#define BAR() asm volatile("s_barrier" ::: "memory")

__global__ __launch_bounds__(T1) void st_pass1(const float* __restrict__ pred,
                                               int* __restrict__ cntPart,
                                               float* __restrict__ snlPart,
                                               float* __restrict__ out) {
    __shared__ float sbuf[NBUF * BUFELE];    // 116736 B staging
    __shared__ int   hcnt[ROW];              // 6080 B
    __shared__ float hsnl[ROW];              // 6080 B  -> total 125.9 KB

    int tid  = threadIdx.x;
    int lane = tid & 63;
    int wid  = tid >> 6;                     // 0..7
    int blk  = blockIdx.x;
    int b    = blk >> 6;                     // / BPI
    int seg  = blk & (BPI - 1);

    if (blk == 0 && tid == 0) out[0] = 0.f;  // pass2 accumulates atomically
    for (int i = tid; i < ROW; i += T1) { hcnt[i] = 0; hsnl[i] = 0.f; }
    __syncthreads();                         // hist ready BEFORE any prefetch

    const float* gbase = pred + (size_t)b * CC * NPIX + (size_t)seg * SEG;

    // issue chunk t into buffer bufsel: 38 instrs (19 ch x 2 halves),
    // wave w issues instr i where i%8==w -> waves 0-5: 5, waves 6-7: 4.
    auto issue = [&](int t, int bufsel) {
        const float* gc = gbase + (size_t)t * CHUNK + lane * 4;
        float* lb = sbuf + bufsel * BUFELE;
        for (int i = wid; i < 2 * CC; i += 8) {
            int c = i >> 1, h = i & 1;
            gload16(gc + (size_t)c * NPIX + h * 256, lb + c * CHUNK + h * 256);
        }
    };

    issue(0, 0);
    issue(1, 1);

    for (int t = 0; t < NCHUNK; ++t) {
        if (t + 2 < NCHUNK) issue(t + 2, (t + 2) % 3);   // buffer freed at iter t-1

        // counted wait for own chunk-t loads: safe lower bound = min per-wave
        // count of chunks t+1,t+2 still allowed outstanding. Never 0 mid-loop.
        if (t < NCHUNK - 2)       asm volatile("s_waitcnt vmcnt(8)" ::: "memory");
        else if (t == NCHUNK - 2) asm volatile("s_waitcnt vmcnt(4)" ::: "memory");
        else                      asm volatile("s_waitcnt vmcnt(0)" ::: "memory");
        BAR();                                // all waves' chunk-t data in LDS

        const float* lb = sbuf + (t % 3) * BUFELE;
        float m = lb[tid];                    // channel 0, pixel tid (2-way free)
        float s = 1.f;
        int arg = 0;
        #pragma unroll
        for (int c = 1; c < CC; ++c) {
            float x  = lb[c * CHUNK + tid];   // ds_read_b32, imm offset c*2048
            float nm = fmaxf(m, x);
            s = s * __expf(m - nm) + __expf(x - nm);
            arg = (x > m) ? c : arg;          // strict > keeps first max
            m = nm;
        }
        float prob = 1.f / s;                 // max softmax prob
        float nll  = __logf(s);               // -log(max_prob)
        int bin = min((int)(prob * (float)NB), NB - 1);
        int idx = arg * NB + bin;
        atomicAdd(&hcnt[idx], 1);             // LDS atomics: CU-local
        atomicAdd(&hsnl[idx], nll);

        BAR();                                // all waves done reading buf[t%3]
    }
    __syncthreads();                          // drain; hist atomics visible

    int*   cp = cntPart + (size_t)blk * ROW;
    float* sp = snlPart + (size_t)blk * ROW;
    for (int i = tid; i < ROW; i += T1) { cp[i] = hcnt[i]; sp[i] = hsnl[i]; }
}

// Fused tail: one block per (b,c) row. 4 threads per bin sum 16 partials each
// (coalesced), LDS combine, thread 0 scans for the rank cutoff and atomically
// adds the row's contribution to out[0] (zeroed by pass1).
__global__ __launch_bounds__(320) void st_pass2(const int* __restrict__ cntPart,
                                                const float* __restrict__ snlPart,
                                                float* __restrict__ out) {
    __shared__ int   pcnt[4][NB];
    __shared__ float psnl[4][NB];
    __shared__ int   scnt[NB];
    __shared__ float ssnl[NB];
    int r = blockIdx.x;                  // 0..75
    int b = r / CC, c = r - b * CC;
    int tid = threadIdx.x;

    {
        int q   = tid / NB;              // partial-quarter 0..3
        int bin = tid - q * NB;
        size_t off = (size_t)(b * BPI + q * 16) * ROW + (size_t)(c * NB + bin);
        int cs0 = 0, cs1 = 0; float ss0 = 0.f, ss1 = 0.f;
        #pragma unroll 8
        for (int p = 0; p < 16; p += 2) {
            cs0 += cntPart[off + (size_t)p * ROW];
            cs1 += cntPart[off + (size_t)(p + 1) * ROW];
            ss0 += snlPart[off + (size_t)p * ROW];
            ss1 += snlPart[off + (size_t)(p + 1) * ROW];
        }
        pcnt[q][bin] = cs0 + cs1;
        psnl[q][bin] = ss0 + ss1;
    }
    __syncthreads();
    if (tid < NB) {
        scnt[tid] = (pcnt[0][tid] + pcnt[1][tid]) + (pcnt[2][tid] + pcnt[3][tid]);
        ssnl[tid] = (psnl[0][tid] + psnl[1][tid]) + (psnl[2][tid] + psnl[3][tid]);
    }
    __syncthreads();

    if (tid == 0) {
        int count = 0;
        #pragma unroll 8
        for (int i = 0; i < NB; ++i) count += scnt[i];
        float conf = 0.f;                // sum of nll where p >= 0.9
        #pragma unroll 8
        for (int i = CONF_BIN; i < NB; ++i) conf += ssnl[i];
        int k = (int)floorf((float)count * FRACTION_F);  // match jnp f32 math
        float sel;
        if (k == 0) {
            sel = conf;
        } else {
            int cum = 0;                 // count in bins strictly above boundary
            float csum = 0.f;
            int bin = NB - 1;
            int hh = 0;
            for (; bin >= 0; --bin) {
                hh = scnt[bin];
                if (cum + hh >= k) break;    // rank k-1 lies in this bin
                cum += hh;
                csum += ssnl[bin];
            }
            if (bin < 0) {
                sel = csum;              // safety (k < count always)
            } else if (bin >= CONF_BIN) {
                sel = conf;              // cutoff >= 0.9 -> union == {p>0.9}
            } else {
                float avg = ssnl[bin] / (float)max(hh, 1);
                sel = csum + (float)(k - cum) * avg;
            }
        }
        atomicAdd(out, sel * (1.0f / (float)(BB * (size_t)NPIX)));
    }
}

extern "C" void kernel_launch(void* const* d_in, const int* in_sizes, int n_in,
                              void* d_out, int out_size, void* d_ws, size_t ws_size,
                              hipStream_t stream) {
    const float* pred = (const float*)d_in[0];
    float* out = (float*)d_out;

    char* ws = (char*)d_ws;
    int*   cntPart = (int*)ws;
    float* snlPart = (float*)(ws + (size_t)NBLK1 * ROW * sizeof(int));

    st_pass1<<<NBLK1, T1, 0, stream>>>(pred, cntPart, snlPart, out);
    st_pass2<<<NROW, 320, 0, stream>>>(cntPart, snlPart, out);
}